// Round 2
// baseline (1288.785 us; speedup 1.0000x reference)
//
#include <hip/hip_runtime.h>
#include <cmath>

#define NS 64
#define NN 128
#define NT 1000

// Mirrors numpy's npy_logaddexpf(x, 0):
//   x == 0 -> LOGE2 ; x > 0 -> x + log1p(exp(-x)) ; x < 0 -> log1p(exp(x))
__device__ __forceinline__ float softplus_np(float x) {
    if (x == 0.0f) return 0.693147180559945309f;   // NPY_LOGE2f (0x3F317218)
    if (x > 0.0f)  return x + log1pf(expf(-x));
    return log1pf(expf(x));
}

__global__ __launch_bounds__(64) void snn_scan_kernel(
    const float* __restrict__ w,
    const float* __restrict__ ic,
    const float* __restrict__ v0,
    const float* __restrict__ i0,
    const float* __restrict__ s0,
    const float* __restrict__ mu,
    const float* __restrict__ sigma,
    const float* __restrict__ noise,      // [T, S, N, 2]
    const float* __restrict__ exp_draws,  // [T, S, N]
    float* __restrict__ out)              // [S, N, T, 3]
{
    #pragma clang fp contract(off)
    __shared__ float wl[NN * NN];         // w row-major, f32, 64 KiB

    const int samp = blockIdx.x;
    const int l = threadIdx.x;            // one wave: lanes 0..63, neurons 2l, 2l+1

    // stage w into LDS (64 float4s per lane)
    {
        const float4* src = (const float4*)w;
        float4* dst = (float4*)wl;
        #pragma unroll
        for (int it = 0; it < (NN * NN / 4) / 64; ++it)
            dst[it * 64 + l] = src[it * 64 + l];
    }
    __syncthreads();

    const int n0 = 2 * l, n1 = 2 * l + 1;
    const float mu1 = mu[0];
    const float negmu2 = -mu[1];          // np computes (-mu2) once; negation is exact
    const float g00 = sigma[0], g01 = sigma[1];
    const float g10 = sigma[2], g11 = sigma[3];
    const float ic0 = ic[n0], ic1 = ic[n1];

    float v_0 = v0[samp * NN + n0], v_1 = v0[samp * NN + n1];
    float i_0 = i0[samp * NN + n0], i_1 = i0[samp * NN + n1];
    float s_0 = s0[samp * NN + n0], s_1 = s0[samp * NN + n1];

    const float SQDT = sqrtf(0.01f);      // == np.sqrt(np.float32(0.01)) == 0x3DCCCCCD
    const float DTf  = 0.01f;

    const float4* nzbase = (const float4*)noise + (size_t)samp * (NN * 2 / 4) + l;
    const size_t  nzstride = (size_t)NS * NN * 2 / 4;     // float4s per timestep
    const float2* edbase = (const float2*)exp_draws + (size_t)samp * (NN / 2) + l;
    const size_t  edstride = (size_t)NS * NN / 2;         // float2s per timestep

    float* outb0 = out + (size_t)(samp * NN + n0) * NT * 3;
    float* outb1 = out + (size_t)(samp * NN + n1) * NT * 3;

    // depth-4 software pipeline, statically indexed register buffers
    float4 nb0 = nzbase[0 * nzstride], nb1 = nzbase[1 * nzstride],
           nb2 = nzbase[2 * nzstride], nb3 = nzbase[3 * nzstride];
    float2 eb0 = edbase[0 * edstride], eb1 = edbase[1 * edstride],
           eb2 = edbase[2 * edstride], eb3 = edbase[3 * edstride];

    auto step = [&](int t, const float4 nz, const float2 ed) {
        #pragma clang fp contract(off)
        // dW = noise * sqrt(DT), elementwise (matches np precompute)
        const float dw00 = nz.x * SQDT, dw01 = nz.y * SQDT;
        const float dw10 = nz.z * SQDT, dw11 = nz.w * SQDT;

        // intensity from carry v (reference computes ds before updates)
        const float sp0 = softplus_np(v_0);
        const float sp1 = softplus_np(v_1);

        // nvi[j] = dw0*sigma[j,0] + dw1*sigma[j,1]  (mul, mul, add — no FMA)
        const float nv0 = (dw00 * g00) + (dw01 * g01);
        const float nv1 = (dw10 * g00) + (dw11 * g01);
        const float ni0 = (dw00 * g10) + (dw01 * g11);
        const float ni1 = (dw10 * g10) + (dw11 * g11);

        // v' = (v + DT*(mu1*((i+ic)-v))) + nv
        {
            const float t0 = (i_0 + ic0) - v_0;
            const float t1 = (i_1 + ic1) - v_1;
            v_0 = (v_0 + DTf * (mu1 * t0)) + nv0;
            v_1 = (v_1 + DTf * (mu1 * t1)) + nv1;
        }
        // i' = (i + DT*((-mu2)*i)) + ni
        i_0 = (i_0 + DTf * (negmu2 * i_0)) + ni0;
        i_1 = (i_1 + DTf * (negmu2 * i_1)) + ni1;
        // s' = s + DT*softplus(v_old)
        s_0 = s_0 + DTf * sp0;
        s_1 = s_1 + DTf * sp1;

        const bool k0 = (s_0 >= 0.0f), k1 = (s_1 >= 0.0f);
        unsigned long long me = __ballot(k0);   // bit b -> neuron 2b
        unsigned long long mo = __ballot(k1);   // bit b -> neuron 2b+1

        // sparse spk @ w, accumulated in ascending neuron order (fp32)
        float a0 = 0.0f, a1 = 0.0f;
        while (me | mo) {
            const int be = me ? __builtin_ctzll(me) : 64;
            const int bo = mo ? __builtin_ctzll(mo) : 64;
            int row;
            if (2 * be < 2 * bo + 1) { row = 2 * be; me &= (me - 1); }
            else                     { row = 2 * bo + 1; mo &= (mo - 1); }
            const float2 wp = *(const float2*)(wl + row * NN + 2 * l);
            a0 = a0 + wp.x;
            a1 = a1 + wp.y;
        }
        i_0 = i_0 + a0;
        i_1 = i_1 + a1;

        if (k0) { v_0 = 0.0f; s_0 = -ed.x; }
        if (k1) { v_1 = 0.0f; s_1 = -ed.y; }

        float* o0 = outb0 + t * 3;
        o0[0] = v_0; o0[1] = i_0; o0[2] = s_0;
        float* o1 = outb1 + t * 3;
        o1[0] = v_1; o1[1] = i_1; o1[2] = s_1;
    };

    for (int t = 0; t < NT; t += 4) {
        step(t + 0, nb0, eb0);
        if (t + 4 < NT) { nb0 = nzbase[(size_t)(t + 4) * nzstride]; eb0 = edbase[(size_t)(t + 4) * edstride]; }
        step(t + 1, nb1, eb1);
        if (t + 5 < NT) { nb1 = nzbase[(size_t)(t + 5) * nzstride]; eb1 = edbase[(size_t)(t + 5) * edstride]; }
        step(t + 2, nb2, eb2);
        if (t + 6 < NT) { nb2 = nzbase[(size_t)(t + 6) * nzstride]; eb2 = edbase[(size_t)(t + 6) * edstride]; }
        step(t + 3, nb3, eb3);
        if (t + 7 < NT) { nb3 = nzbase[(size_t)(t + 7) * nzstride]; eb3 = edbase[(size_t)(t + 7) * edstride]; }
    }
}

extern "C" void kernel_launch(void* const* d_in, const int* in_sizes, int n_in,
                              void* d_out, int out_size, void* d_ws, size_t ws_size,
                              hipStream_t stream) {
    const float* w         = (const float*)d_in[0];
    const float* ic        = (const float*)d_in[1];
    const float* v0        = (const float*)d_in[2];
    const float* i0        = (const float*)d_in[3];
    const float* s0        = (const float*)d_in[4];
    const float* mu        = (const float*)d_in[5];
    const float* sigma     = (const float*)d_in[6];
    const float* noise     = (const float*)d_in[7];
    const float* exp_draws = (const float*)d_in[8];
    float* out = (float*)d_out;

    snn_scan_kernel<<<dim3(NS), dim3(64), 0, stream>>>(
        w, ic, v0, i0, s0, mu, sigma, noise, exp_draws, out);
}

// Round 3
// 810.361 us; speedup vs baseline: 1.5904x; 1.5904x over previous
//
#include <hip/hip_runtime.h>
#include <cmath>

#define NS 64
#define NN 128
#define NT 1000
#define CH 8                               // steps buffered in LDS per flush
#define ROWDW (NN * 3 + 8)                 // 392 dwords per buffered step-row
#define WL_DW (NN * NN)                    // 16384 dwords of w
#define LDS_BYTES ((WL_DW + CH * ROWDW) * 4)   // 65536 + 12544 = 78080

// == npy_logaddexpf(x, 0), branch-free but bit-identical:
//   x>0: fmax=x, |x|=x  -> x + log1p(exp(-x))      (same ops as npy)
//   x<0: fmax=0, |x|=-x -> 0 + log1p(exp(x)) = exact (y>0)
//   x==0: exact select of LOGE2f
__device__ __forceinline__ float softplus_np(float x) {
    float r = fmaxf(x, 0.0f) + log1pf(expf(-fabsf(x)));
    return (x == 0.0f) ? 0.693147180559945309f : r;
}

__global__ __launch_bounds__(64) void snn_scan_kernel(
    const float* __restrict__ w,
    const float* __restrict__ ic,
    const float* __restrict__ v0,
    const float* __restrict__ i0,
    const float* __restrict__ s0,
    const float* __restrict__ mu,
    const float* __restrict__ sigma,
    const float* __restrict__ noise,      // [T, S, N, 2]
    const float* __restrict__ exp_draws,  // [T, S, N]
    float* __restrict__ out)              // [S, N, T, 3]
{
    #pragma clang fp contract(off)
    extern __shared__ float smem[];
    float* wl   = smem;                   // [128][128] f32
    float* obuf = smem + WL_DW;           // [CH][ROWDW] f32 output staging

    const int samp = blockIdx.x;
    const int l = threadIdx.x;            // one wave: lanes 0..63, neurons 2l, 2l+1

    {   // stage w into LDS (64 float4s per lane)
        const float4* src = (const float4*)w;
        float4* dst = (float4*)wl;
        #pragma unroll
        for (int it = 0; it < (NN * NN / 4) / 64; ++it)
            dst[it * 64 + l] = src[it * 64 + l];
    }
    __syncthreads();

    const float mu1 = mu[0];
    const float negmu2 = -mu[1];
    const float g00 = sigma[0], g01 = sigma[1];
    const float g10 = sigma[2], g11 = sigma[3];
    const float ic0 = ic[2 * l], ic1 = ic[2 * l + 1];

    float v_0 = v0[samp * NN + 2 * l], v_1 = v0[samp * NN + 2 * l + 1];
    float i_0 = i0[samp * NN + 2 * l], i_1 = i0[samp * NN + 2 * l + 1];
    float s_0 = s0[samp * NN + 2 * l], s_1 = s0[samp * NN + 2 * l + 1];
    float sp_0 = softplus_np(v_0);        // intensity of carry v, pipelined
    float sp_1 = softplus_np(v_1);

    const float SQDT = sqrtf(0.01f);      // 0x3DCCCCCD, == np.sqrt(float32(0.01))
    const float DTf  = 0.01f;
    const float LOGE2 = 0.693147180559945309f;

    const float4* nzbase = (const float4*)noise + (size_t)samp * (NN * 2 / 4) + l;
    const size_t  nzstride = (size_t)NS * NN * 2 / 4;
    const float2* edbase = (const float2*)exp_draws + (size_t)samp * (NN / 2) + l;
    const size_t  edstride = (size_t)NS * NN / 2;

    float* outb = out + (size_t)samp * NN * NT * 3;

    // depth-4 software pipeline, statically named register buffers
    float4 nb0 = nzbase[0 * nzstride], nb1 = nzbase[1 * nzstride],
           nb2 = nzbase[2 * nzstride], nb3 = nzbase[3 * nzstride];
    float2 eb0 = edbase[0 * edstride], eb1 = edbase[1 * edstride],
           eb2 = edbase[2 * edstride], eb3 = edbase[3 * edstride];

    auto pf = [&](float4& nb, float2& eb, int tt) {
        if (tt < NT) { nb = nzbase[(size_t)tt * nzstride]; eb = edbase[(size_t)tt * edstride]; }
    };

    auto step = [&](int tm, const float4 nz, const float2 ed) {
        #pragma clang fp contract(off)
        const float dw00 = nz.x * SQDT, dw01 = nz.y * SQDT;
        const float dw10 = nz.z * SQDT, dw11 = nz.w * SQDT;

        const float nv0 = (dw00 * g00) + (dw01 * g01);
        const float nv1 = (dw10 * g00) + (dw11 * g01);
        const float ni0 = (dw00 * g10) + (dw01 * g11);
        const float ni1 = (dw10 * g10) + (dw11 * g11);

        const float t0 = (i_0 + ic0) - v_0;
        const float t1 = (i_1 + ic1) - v_1;
        const float vt0 = (v_0 + DTf * (mu1 * t0)) + nv0;
        const float vt1 = (v_1 + DTf * (mu1 * t1)) + nv1;
        const float it0 = (i_0 + DTf * (negmu2 * i_0)) + ni0;
        const float it1 = (i_1 + DTf * (negmu2 * i_1)) + ni1;
        s_0 = s_0 + DTf * sp_0;           // sp_* = softplus(carry v), precomputed
        s_1 = s_1 + DTf * sp_1;

        const bool k0 = (s_0 >= 0.0f), k1 = (s_1 >= 0.0f);
        unsigned long long me = __ballot(k0);   // bit b -> neuron 2b
        unsigned long long mo = __ballot(k1);   // bit b -> neuron 2b+1

        // speculative next-step softplus: long transcendental chain overlaps
        // the sparse coupling loop below (softplus(0) handled by exact select)
        const float spv0 = softplus_np(vt0);
        const float spv1 = softplus_np(vt1);

        // sparse spk @ w, ascending neuron order, pairwise LDS loads
        float a0 = 0.0f, a1 = 0.0f;
        while (me | mo) {
            int be = me ? (int)__builtin_ctzll(me) : 99;
            int bo = mo ? (int)__builtin_ctzll(mo) : 99;
            int r1;
            if (2 * be < 2 * bo + 1) { r1 = 2 * be; me &= (me - 1); }
            else                     { r1 = 2 * bo + 1; mo &= (mo - 1); }
            const bool h2 = (me | mo) != 0ull;
            int r2 = r1;
            if (h2) {
                int be2 = me ? (int)__builtin_ctzll(me) : 99;
                int bo2 = mo ? (int)__builtin_ctzll(mo) : 99;
                if (2 * be2 < 2 * bo2 + 1) { r2 = 2 * be2; me &= (me - 1); }
                else                       { r2 = 2 * bo2 + 1; mo &= (mo - 1); }
            }
            const float2 w1 = *(const float2*)(wl + r1 * NN + 2 * l);
            const float2 w2 = *(const float2*)(wl + r2 * NN + 2 * l);
            a0 = a0 + w1.x; a1 = a1 + w1.y;
            if (h2) { a0 = a0 + w2.x; a1 = a1 + w2.y; }
        }
        i_0 = it0 + a0;
        i_1 = it1 + a1;

        v_0 = k0 ? 0.0f : vt0;      v_1 = k1 ? 0.0f : vt1;
        s_0 = k0 ? -ed.x : s_0;     s_1 = k1 ? -ed.y : s_1;
        sp_0 = k0 ? LOGE2 : spv0;   sp_1 = k1 ? LOGE2 : spv1;

        // stage (v,i,s)x2 into LDS: 3x ds_write_b64, no vm-ops per step
        float* row = obuf + tm * ROWDW + 6 * l;
        *(float2*)(row)     = make_float2(v_0, i_0);
        *(float2*)(row + 2) = make_float2(s_0, v_1);
        *(float2*)(row + 4) = make_float2(i_1, s_1);
    };

    auto flush = [&](int tb) {
        // 8 steps x 128 neurons x 12B = 12KB; each neuron's run (96B) is
        // contiguous in global: [n][tb..tb+7][3]. Emit as float2 stores,
        // 12 consecutive lanes cover one run -> ~6 address clusters/store.
        #pragma unroll
        for (int j = 0; j < 24; ++j) {
            const int f = j * 64 + l;       // 0..1535 float2-slots
            const int n = f / 12;           // neuron
            const int r = f % 12;           // float2-slot within 96B run
            const int da = 2 * r, db = 2 * r + 1;   // dwords in [8][3] run
            const float x = obuf[(da / 3) * ROWDW + n * 3 + (da % 3)];
            const float y = obuf[(db / 3) * ROWDW + n * 3 + (db % 3)];
            *(float2*)(outb + (size_t)n * (NT * 3) + tb * 3 + da) = make_float2(x, y);
        }
    };

    for (int tb = 0; tb < NT; tb += CH) {
        step(0, nb0, eb0); pf(nb0, eb0, tb + 4);
        step(1, nb1, eb1); pf(nb1, eb1, tb + 5);
        step(2, nb2, eb2); pf(nb2, eb2, tb + 6);
        step(3, nb3, eb3); pf(nb3, eb3, tb + 7);
        step(4, nb0, eb0); pf(nb0, eb0, tb + 8);
        step(5, nb1, eb1); pf(nb1, eb1, tb + 9);
        step(6, nb2, eb2); pf(nb2, eb2, tb + 10);
        step(7, nb3, eb3); pf(nb3, eb3, tb + 11);
        flush(tb);
    }
}

extern "C" void kernel_launch(void* const* d_in, const int* in_sizes, int n_in,
                              void* d_out, int out_size, void* d_ws, size_t ws_size,
                              hipStream_t stream) {
    const float* w         = (const float*)d_in[0];
    const float* ic        = (const float*)d_in[1];
    const float* v0        = (const float*)d_in[2];
    const float* i0        = (const float*)d_in[3];
    const float* s0        = (const float*)d_in[4];
    const float* mu        = (const float*)d_in[5];
    const float* sigma     = (const float*)d_in[6];
    const float* noise     = (const float*)d_in[7];
    const float* exp_draws = (const float*)d_in[8];
    float* out = (float*)d_out;

    // >64KB LDS requires the dynamic-size opt-in (host-side attribute set;
    // not a stream op -> graph-capture-safe, idempotent, deterministic)
    (void)hipFuncSetAttribute((const void*)snn_scan_kernel,
                              hipFuncAttributeMaxDynamicSharedMemorySize,
                              LDS_BYTES);

    snn_scan_kernel<<<dim3(NS), dim3(64), LDS_BYTES, stream>>>(
        w, ic, v0, i0, s0, mu, sigma, noise, exp_draws, out);
}

// Round 4
// 799.779 us; speedup vs baseline: 1.6114x; 1.0132x over previous
//
#include <hip/hip_runtime.h>
#include <cmath>

#define NS 64
#define NN 128
#define NT 1000
#define CH 4                                // steps per obuf half-buffer
#define ROWDW (NN * 3 + 8)                  // 392 dwords per buffered step-row
#define WROWS 130                           // 128 rows of w + 2 zero rows
#define WL_DW (WROWS * NN)                  // 16640
#define OBUF_DW (2 * CH * ROWDW)            // 3136 (double-buffered)
#define LDS_BYTES ((WL_DW + OBUF_DW) * 4)   // 66560 + 12544 = 79104

// == npy_logaddexpf(x, 0), branch-free but bit-identical:
//   x>0: fmax=x, |x|=x  -> x + log1p(exp(-x)) ; x<0: 0 + log1p(exp(x)) ; x==0 -> LOGE2
__device__ __forceinline__ float softplus_np(float x) {
    float r = fmaxf(x, 0.0f) + log1pf(expf(-fabsf(x)));
    return (x == 0.0f) ? 0.693147180559945309f : r;
}

__global__ __launch_bounds__(128) void snn_scan_kernel(
    const float* __restrict__ w,
    const float* __restrict__ ic,
    const float* __restrict__ v0,
    const float* __restrict__ i0,
    const float* __restrict__ s0,
    const float* __restrict__ mu,
    const float* __restrict__ sigma,
    const float* __restrict__ noise,      // [T, S, N, 2]
    const float* __restrict__ exp_draws,  // [T, S, N]
    float* __restrict__ out)              // [S, N, T, 3]
{
    #pragma clang fp contract(off)
    extern __shared__ float smem[];
    float* wl   = smem;                   // [130][128]: w rows + 2 zero rows
    float* obuf = smem + WL_DW;           // [2][CH][ROWDW] output staging

    const int samp = blockIdx.x;
    const int tid  = threadIdx.x;
    const int wid  = tid >> 6;            // wave 0 = compute, wave 1 = flush
    const int l    = tid & 63;

    {   // cooperative stage of w (4096 float4 / 128 threads) + zero rows
        const float4* src = (const float4*)w;
        float4* dst = (float4*)wl;
        #pragma unroll
        for (int it = 0; it < 32; ++it)
            dst[it * 128 + tid] = src[it * 128 + tid];
        ((float2*)(wl + 128 * NN))[tid] = make_float2(0.0f, 0.0f);
    }
    __syncthreads();

    const float SQDT  = sqrtf(0.01f);     // 0x3DCCCCCD == np.sqrt(float32(0.01))
    const float DTf   = 0.01f;
    const float LOGE2 = 0.693147180559945309f;

    const float4* nzbase = (const float4*)noise + (size_t)samp * (NN * 2 / 4) + l;
    const size_t  nzstride = (size_t)NS * NN * 2 / 4;
    const float2* edbase = (const float2*)exp_draws + (size_t)samp * (NN / 2) + l;
    const size_t  edstride = (size_t)NS * NN / 2;
    float* outb = out + (size_t)samp * NN * NT * 3;

    float mu1 = 0.f, negmu2 = 0.f, g00 = 0.f, g01 = 0.f, g10 = 0.f, g11 = 0.f;
    float ic0 = 0.f, ic1 = 0.f;
    float v_0 = 0.f, v_1 = 0.f, i_0 = 0.f, i_1 = 0.f, s_0 = 0.f, s_1 = 0.f;
    float sp_0 = 0.f, sp_1 = 0.f;
    float4 nb0 = {}, nb1 = {}, nb2 = {}, nb3 = {};
    float2 eb0 = {}, eb1 = {}, eb2 = {}, eb3 = {};

    if (wid == 0) {
        mu1 = mu[0]; negmu2 = -mu[1];
        g00 = sigma[0]; g01 = sigma[1]; g10 = sigma[2]; g11 = sigma[3];
        ic0 = ic[2 * l]; ic1 = ic[2 * l + 1];
        v_0 = v0[samp * NN + 2 * l]; v_1 = v0[samp * NN + 2 * l + 1];
        i_0 = i0[samp * NN + 2 * l]; i_1 = i0[samp * NN + 2 * l + 1];
        s_0 = s0[samp * NN + 2 * l]; s_1 = s0[samp * NN + 2 * l + 1];
        sp_0 = softplus_np(v_0); sp_1 = softplus_np(v_1);
        nb0 = nzbase[0 * nzstride]; nb1 = nzbase[1 * nzstride];
        nb2 = nzbase[2 * nzstride]; nb3 = nzbase[3 * nzstride];
        eb0 = edbase[0 * edstride]; eb1 = edbase[1 * edstride];
        eb2 = edbase[2 * edstride]; eb3 = edbase[3 * edstride];
    }

    const float2* wl2 = (const float2*)wl;

    auto pf = [&](float4& nb, float2& eb, int tt) {   // branchless, clamped
        const int tc = tt < NT ? tt : NT - 1;
        nb = nzbase[(size_t)tc * nzstride];
        eb = edbase[(size_t)tc * edstride];
    };

    auto doStep = [&](int tm, const float4 nz, const float2 ed, float* orow) {
        #pragma clang fp contract(off)
        const float dw00 = nz.x * SQDT, dw01 = nz.y * SQDT;
        const float dw10 = nz.z * SQDT, dw11 = nz.w * SQDT;

        const float nv0 = (dw00 * g00) + (dw01 * g01);
        const float nv1 = (dw10 * g00) + (dw11 * g01);
        const float ni0 = (dw00 * g10) + (dw01 * g11);
        const float ni1 = (dw10 * g10) + (dw11 * g11);

        const float t0 = (i_0 + ic0) - v_0;
        const float t1 = (i_1 + ic1) - v_1;
        const float vt0 = (v_0 + DTf * (mu1 * t0)) + nv0;
        const float vt1 = (v_1 + DTf * (mu1 * t1)) + nv1;
        const float it0 = (i_0 + DTf * (negmu2 * i_0)) + ni0;
        const float it1 = (i_1 + DTf * (negmu2 * i_1)) + ni1;
        s_0 = s_0 + DTf * sp_0;           // sp_* = softplus(carry v), pipelined
        s_1 = s_1 + DTf * sp_1;

        const bool k0 = (s_0 >= 0.0f), k1 = (s_1 >= 0.0f);
        unsigned long long me = __ballot(k0);   // bit b -> neuron 2b
        unsigned long long mo = __ballot(k1);   // bit b -> neuron 2b+1

        // speculative next-step softplus overlaps the coupling below
        const float spv0 = softplus_np(vt0);
        const float spv1 = softplus_np(vt1);

        // branchless extraction of next spiking neuron in ascending order;
        // empty masks yield dummy zero-rows 128/129 (adds exact +0.0)
        auto ext1 = [&]() -> int {
            const int be = me ? (int)__builtin_ctzll(me) : 64;
            const int bo = mo ? (int)__builtin_ctzll(mo) : 64;
            const int ce = 2 * be, co = 2 * bo + 1;
            const bool te = ce < co;
            const unsigned long long me2 = me & (me - 1);
            const unsigned long long mo2 = mo & (mo - 1);
            me = te ? me2 : me;
            mo = te ? mo : mo2;
            return te ? ce : co;
        };
        const int r1 = ext1(); const int r2 = ext1();
        const int r3 = ext1(); const int r4 = ext1();
        const float2 q1 = wl2[r1 * 64 + l];   // 4 independent ds_read_b64
        const float2 q2 = wl2[r2 * 64 + l];
        const float2 q3 = wl2[r3 * 64 + l];
        const float2 q4 = wl2[r4 * 64 + l];
        float a0 = q1.x, a1 = q1.y;           // ascending-order fp32 sum
        a0 += q2.x; a1 += q2.y;
        a0 += q3.x; a1 += q3.y;
        a0 += q4.x; a1 += q4.y;
        if (me | mo) {                        // >=5 spikes: rare (~0.4%)
            do {
                const int r = ext1();
                const float2 q = wl2[r * 64 + l];
                a0 += q.x; a1 += q.y;
            } while (me | mo);
        }
        i_0 = it0 + a0;
        i_1 = it1 + a1;

        v_0 = k0 ? 0.0f : vt0;      v_1 = k1 ? 0.0f : vt1;
        s_0 = k0 ? -ed.x : s_0;     s_1 = k1 ? -ed.y : s_1;
        sp_0 = k0 ? LOGE2 : spv0;   sp_1 = k1 ? LOGE2 : spv1;

        float* row = orow + tm * ROWDW;
        *(float2*)(row)     = make_float2(v_0, i_0);
        *(float2*)(row + 2) = make_float2(s_0, v_1);
        *(float2*)(row + 4) = make_float2(i_1, s_1);
    };

    auto flushBuf = [&](int b, int tb0) {
        // CH steps x 128 neurons x 12B; each neuron's run ([CH][3] dwords = 48B)
        // contiguous in global at outb + n*NT*3 + tb0*3
        const float* ob = obuf + b * (CH * ROWDW);
        #pragma unroll
        for (int j = 0; j < 12; ++j) {
            const int f = j * 64 + l;        // float2 slot 0..767
            const int n = f / 6;             // neuron
            const int r = f - n * 6;         // float2 slot within run
            const int da = 2 * r;
            const float x = ob[((da    ) / 3) * ROWDW + n * 3 + ((da    ) % 3)];
            const float y = ob[((da + 1) / 3) * ROWDW + n * 3 + ((da + 1) % 3)];
            *(float2*)(outb + (size_t)n * (NT * 3) + (size_t)tb0 * 3 + da) =
                make_float2(x, y);
        }
    };

    int cur = 0;
    for (int tb = 0; tb < NT; tb += CH) {
        if (wid == 0) {
            float* orow = obuf + cur * (CH * ROWDW) + 6 * l;
            doStep(0, nb0, eb0, orow); pf(nb0, eb0, tb + 4);
            doStep(1, nb1, eb1, orow); pf(nb1, eb1, tb + 5);
            doStep(2, nb2, eb2, orow); pf(nb2, eb2, tb + 6);
            doStep(3, nb3, eb3, orow); pf(nb3, eb3, tb + 7);
        } else if (tb != 0) {
            flushBuf(cur ^ 1, tb - CH);
        }
        __syncthreads();
        cur ^= 1;
    }
    if (wid == 1) flushBuf(cur ^ 1, NT - CH);   // last block
}

extern "C" void kernel_launch(void* const* d_in, const int* in_sizes, int n_in,
                              void* d_out, int out_size, void* d_ws, size_t ws_size,
                              hipStream_t stream) {
    const float* w         = (const float*)d_in[0];
    const float* ic        = (const float*)d_in[1];
    const float* v0        = (const float*)d_in[2];
    const float* i0        = (const float*)d_in[3];
    const float* s0        = (const float*)d_in[4];
    const float* mu        = (const float*)d_in[5];
    const float* sigma     = (const float*)d_in[6];
    const float* noise     = (const float*)d_in[7];
    const float* exp_draws = (const float*)d_in[8];
    float* out = (float*)d_out;

    (void)hipFuncSetAttribute((const void*)snn_scan_kernel,
                              hipFuncAttributeMaxDynamicSharedMemorySize,
                              LDS_BYTES);

    snn_scan_kernel<<<dim3(NS), dim3(128), LDS_BYTES, stream>>>(
        w, ic, v0, i0, s0, mu, sigma, noise, exp_draws, out);
}

// Round 5
// 726.788 us; speedup vs baseline: 1.7733x; 1.1004x over previous
//
#include <hip/hip_runtime.h>
#include <cmath>

#define NS 64
#define NN 128
#define NT 1000
#define CH 8                                // steps per obuf half-buffer
#define ROWDW (NN * 3 + 8)                  // 392 dwords per buffered step-row
#define WROWS 130                           // 128 rows of w + 2 zero rows
#define WL_DW (WROWS * NN)                  // 16640
#define OBUF_DW (2 * CH * ROWDW)            // 6272 (double-buffered)
#define LDS_BYTES ((WL_DW + OBUF_DW) * 4)   // 66560 + 25088 = 91648

// == npy_logaddexpf(x, 0), branch-free but bit-identical:
//   x>0: fmax=x, |x|=x  -> x + log1p(exp(-x)) ; x<0: 0 + log1p(exp(x)) ; x==0 -> LOGE2
__device__ __forceinline__ float softplus_np(float x) {
    float r = fmaxf(x, 0.0f) + log1pf(expf(-fabsf(x)));
    return (x == 0.0f) ? 0.693147180559945309f : r;
}

// Barrier WITHOUT the compiler's vmcnt(0) drain: LDS-visibility only.
// Prefetch loads stay in flight across blocks (T3/T4: never drain vmcnt).
__device__ __forceinline__ void sync_lds() {
    __builtin_amdgcn_sched_barrier(0);
    asm volatile("s_waitcnt lgkmcnt(0)" ::: "memory");
    __builtin_amdgcn_s_barrier();
    __builtin_amdgcn_sched_barrier(0);
}

__global__ __launch_bounds__(128) void snn_scan_kernel(
    const float* __restrict__ w,
    const float* __restrict__ ic,
    const float* __restrict__ v0,
    const float* __restrict__ i0,
    const float* __restrict__ s0,
    const float* __restrict__ mu,
    const float* __restrict__ sigma,
    const float* __restrict__ noise,      // [T, S, N, 2]
    const float* __restrict__ exp_draws,  // [T, S, N]
    float* __restrict__ out)              // [S, N, T, 3]
{
    #pragma clang fp contract(off)
    extern __shared__ float smem[];
    float* wl   = smem;                   // [130][128]: w rows + 2 zero rows
    float* obuf = smem + WL_DW;           // [2][CH][ROWDW] output staging

    const int samp = blockIdx.x;
    const int tid  = threadIdx.x;
    const int wid  = tid >> 6;            // wave 0 = compute, wave 1 = flush
    const int l    = tid & 63;

    {   // cooperative stage of w (4096 float4 / 128 threads) + zero rows
        const float4* src = (const float4*)w;
        float4* dst = (float4*)wl;
        #pragma unroll
        for (int it = 0; it < 32; ++it)
            dst[it * 128 + tid] = src[it * 128 + tid];
        ((float2*)(wl + 128 * NN))[tid] = make_float2(0.0f, 0.0f);
    }
    sync_lds();

    const float SQDT  = sqrtf(0.01f);     // 0x3DCCCCCD == np.sqrt(float32(0.01))
    const float DTf   = 0.01f;
    const float LOGE2 = 0.693147180559945309f;

    const float4* nzbase = (const float4*)noise + (size_t)samp * (NN * 2 / 4) + l;
    const size_t  nzstride = (size_t)NS * NN * 2 / 4;
    const float2* edbase = (const float2*)exp_draws + (size_t)samp * (NN / 2) + l;
    const size_t  edstride = (size_t)NS * NN / 2;
    float* outb = out + (size_t)samp * NN * NT * 3;

    float mu1 = 0.f, negmu2 = 0.f, g00 = 0.f, g01 = 0.f, g10 = 0.f, g11 = 0.f;
    float ic0 = 0.f, ic1 = 0.f;
    float v_0 = 0.f, v_1 = 0.f, i_0 = 0.f, i_1 = 0.f, s_0 = 0.f, s_1 = 0.f;
    float sp_0 = 0.f, sp_1 = 0.f;
    float4 nb0 = {}, nb1 = {}, nb2 = {}, nb3 = {}, nb4 = {}, nb5 = {}, nb6 = {}, nb7 = {};
    float2 eb0 = {}, eb1 = {}, eb2 = {}, eb3 = {}, eb4 = {}, eb5 = {}, eb6 = {}, eb7 = {};

    if (wid == 0) {
        __builtin_amdgcn_s_setprio(1);    // compute wave owns the critical path
        mu1 = mu[0]; negmu2 = -mu[1];
        g00 = sigma[0]; g01 = sigma[1]; g10 = sigma[2]; g11 = sigma[3];
        ic0 = ic[2 * l]; ic1 = ic[2 * l + 1];
        v_0 = v0[samp * NN + 2 * l]; v_1 = v0[samp * NN + 2 * l + 1];
        i_0 = i0[samp * NN + 2 * l]; i_1 = i0[samp * NN + 2 * l + 1];
        s_0 = s0[samp * NN + 2 * l]; s_1 = s0[samp * NN + 2 * l + 1];
        sp_0 = softplus_np(v_0); sp_1 = softplus_np(v_1);
        nb0 = nzbase[0 * nzstride]; eb0 = edbase[0 * edstride];
        nb1 = nzbase[1 * nzstride]; eb1 = edbase[1 * edstride];
        nb2 = nzbase[2 * nzstride]; eb2 = edbase[2 * edstride];
        nb3 = nzbase[3 * nzstride]; eb3 = edbase[3 * edstride];
        nb4 = nzbase[4 * nzstride]; eb4 = edbase[4 * edstride];
        nb5 = nzbase[5 * nzstride]; eb5 = edbase[5 * edstride];
        nb6 = nzbase[6 * nzstride]; eb6 = edbase[6 * edstride];
        nb7 = nzbase[7 * nzstride]; eb7 = edbase[7 * edstride];
    }

    const float2* wl2 = (const float2*)wl;

    auto pf = [&](float4& nb, float2& eb, int tt) {   // branchless, clamped
        const int tc = tt < NT ? tt : NT - 1;
        nb = nzbase[(size_t)tc * nzstride];
        eb = edbase[(size_t)tc * edstride];
    };

    auto doStep = [&](int tm, const float4 nz, const float2 ed, float* orow) {
        #pragma clang fp contract(off)
        const float dw00 = nz.x * SQDT, dw01 = nz.y * SQDT;
        const float dw10 = nz.z * SQDT, dw11 = nz.w * SQDT;

        const float nv0 = (dw00 * g00) + (dw01 * g01);
        const float nv1 = (dw10 * g00) + (dw11 * g01);
        const float ni0 = (dw00 * g10) + (dw01 * g11);
        const float ni1 = (dw10 * g10) + (dw11 * g11);

        const float t0 = (i_0 + ic0) - v_0;
        const float t1 = (i_1 + ic1) - v_1;
        const float vt0 = (v_0 + DTf * (mu1 * t0)) + nv0;
        const float vt1 = (v_1 + DTf * (mu1 * t1)) + nv1;
        const float it0 = (i_0 + DTf * (negmu2 * i_0)) + ni0;
        const float it1 = (i_1 + DTf * (negmu2 * i_1)) + ni1;
        s_0 = s_0 + DTf * sp_0;           // sp_* = softplus(carry v), pipelined
        s_1 = s_1 + DTf * sp_1;

        const bool k0 = (s_0 >= 0.0f), k1 = (s_1 >= 0.0f);
        unsigned long long me = __ballot(k0);   // bit b -> neuron 2b
        unsigned long long mo = __ballot(k1);   // bit b -> neuron 2b+1

        // speculative next-step softplus; VALU issue overlaps coupling LDS wait
        const float spv0 = softplus_np(vt0);
        const float spv1 = softplus_np(vt1);

        float a0 = 0.0f, a1 = 0.0f;
        if (me | mo) {                    // wave-uniform skip of empty steps
            auto ext1 = [&]() -> int {    // ascending-order extraction;
                const int be = me ? (int)__builtin_ctzll(me) : 64;   // empty ->
                const int bo = mo ? (int)__builtin_ctzll(mo) : 64;   // zero-rows
                const int ce = 2 * be, co = 2 * bo + 1;
                const bool te = ce < co;
                const unsigned long long me2 = me & (me - 1);
                const unsigned long long mo2 = mo & (mo - 1);
                me = te ? me2 : me;
                mo = te ? mo : mo2;
                return te ? ce : co;
            };
            const int r1 = ext1(); const int r2 = ext1();
            const int r3 = ext1(); const int r4 = ext1();
            const float2 q1 = wl2[r1 * 64 + l];   // 4 independent ds_read_b64
            const float2 q2 = wl2[r2 * 64 + l];
            const float2 q3 = wl2[r3 * 64 + l];
            const float2 q4 = wl2[r4 * 64 + l];
            a0 = q1.x;  a1 = q1.y;                // ascending-order fp32 sum
            a0 += q2.x; a1 += q2.y;
            a0 += q3.x; a1 += q3.y;
            a0 += q4.x; a1 += q4.y;
            if (me | mo) {                        // >=5 spikes: rare
                do {
                    const int r = ext1();
                    const float2 q = wl2[r * 64 + l];
                    a0 += q.x; a1 += q.y;
                } while (me | mo);
            }
        }
        i_0 = it0 + a0;                   // unconditional add: bit-identical
        i_1 = it1 + a1;

        v_0 = k0 ? 0.0f : vt0;      v_1 = k1 ? 0.0f : vt1;
        s_0 = k0 ? -ed.x : s_0;     s_1 = k1 ? -ed.y : s_1;
        sp_0 = k0 ? LOGE2 : spv0;   sp_1 = k1 ? LOGE2 : spv1;

        float* row = orow + tm * ROWDW;
        *(float2*)(row)     = make_float2(v_0, i_0);
        *(float2*)(row + 2) = make_float2(s_0, v_1);
        *(float2*)(row + 4) = make_float2(i_1, s_1);
    };

    auto flushBuf = [&](int b, int tb0) {
        // CH steps x 128 neurons x 12B; each neuron's run ([CH][3] dwords = 96B)
        // contiguous in global at outb + n*NT*3 + tb0*3
        const float* ob = obuf + b * (CH * ROWDW);
        #pragma unroll
        for (int j = 0; j < 24; ++j) {
            const int f = j * 64 + l;        // float2 slot 0..1535
            const int n = f / 12;            // neuron
            const int r = f - n * 12;        // float2 slot within run
            const int da = 2 * r;
            const float x = ob[((da    ) / 3) * ROWDW + n * 3 + ((da    ) % 3)];
            const float y = ob[((da + 1) / 3) * ROWDW + n * 3 + ((da + 1) % 3)];
            *(float2*)(outb + (size_t)n * (NT * 3) + (size_t)tb0 * 3 + da) =
                make_float2(x, y);
        }
    };

    int cur = 0;
    for (int tb = 0; tb < NT; tb += CH) {
        if (wid == 0) {
            float* orow = obuf + cur * (CH * ROWDW) + 6 * l;
            doStep(0, nb0, eb0, orow); pf(nb0, eb0, tb + 8);
            doStep(1, nb1, eb1, orow); pf(nb1, eb1, tb + 9);
            doStep(2, nb2, eb2, orow); pf(nb2, eb2, tb + 10);
            doStep(3, nb3, eb3, orow); pf(nb3, eb3, tb + 11);
            doStep(4, nb4, eb4, orow); pf(nb4, eb4, tb + 12);
            doStep(5, nb5, eb5, orow); pf(nb5, eb5, tb + 13);
            doStep(6, nb6, eb6, orow); pf(nb6, eb6, tb + 14);
            doStep(7, nb7, eb7, orow); pf(nb7, eb7, tb + 15);
        } else if (tb != 0) {
            flushBuf(cur ^ 1, tb - CH);
        }
        sync_lds();                       // lgkm-only barrier: vm stays in flight
        cur ^= 1;
    }
    if (wid == 1) flushBuf(cur ^ 1, NT - CH);   // last block

    __builtin_amdgcn_s_setprio(0);
}

extern "C" void kernel_launch(void* const* d_in, const int* in_sizes, int n_in,
                              void* d_out, int out_size, void* d_ws, size_t ws_size,
                              hipStream_t stream) {
    const float* w         = (const float*)d_in[0];
    const float* ic        = (const float*)d_in[1];
    const float* v0        = (const float*)d_in[2];
    const float* i0        = (const float*)d_in[3];
    const float* s0        = (const float*)d_in[4];
    const float* mu        = (const float*)d_in[5];
    const float* sigma     = (const float*)d_in[6];
    const float* noise     = (const float*)d_in[7];
    const float* exp_draws = (const float*)d_in[8];
    float* out = (float*)d_out;

    (void)hipFuncSetAttribute((const void*)snn_scan_kernel,
                              hipFuncAttributeMaxDynamicSharedMemorySize,
                              LDS_BYTES);

    snn_scan_kernel<<<dim3(NS), dim3(128), LDS_BYTES, stream>>>(
        w, ic, v0, i0, s0, mu, sigma, noise, exp_draws, out);
}